// Round 9
// baseline (353.444 us; speedup 1.0000x reference)
//
#include <hip/hip_runtime.h>

#define NN 4096
#define BB 32
#define UU 64
#define MAXNNZ 96

typedef float f32x4 __attribute__((ext_vector_type(4)));
typedef float f32x2 __attribute__((ext_vector_type(2)));
typedef short bf16x8 __attribute__((ext_vector_type(8)));
typedef unsigned short us8 __attribute__((ext_vector_type(8)));
typedef unsigned short us4 __attribute__((ext_vector_type(4)));

__device__ __forceinline__ float bf2f(unsigned short u) {
    return __uint_as_float(((unsigned)u) << 16);
}
__device__ __forceinline__ unsigned short f2bf(float f) {
    unsigned x = __float_as_uint(f);
    x += 0x7fffu + ((x >> 16) & 1u);
    return (unsigned short)(x >> 16);
}

// Packed column order within each 2048-wide src (b in 0..31, d in 0..63):
//   off(b,d) = (d>>5)*1024 + (b>>4)*512 + ((d>>3)&3)*128 + (b&15)*8 + (d&7)
// i.e. [dwin][g][kg][lr][e] -- exactly the MFMA B-fragment load order.

// ---------------------------------------------------------------------------
// K1: dense support (4096x4096 f32) -> padded ELL (cols int32, vals f32, cnt)
// Rows padded with (col=0, val=0) to a multiple of 8 (pad gathers are L2-hot
// row 0, fma x0 = no-op) so the SpMM pipeline loop is branch-free.
// ---------------------------------------------------------------------------
__global__ void build_ell(const float* __restrict__ sup, int* __restrict__ cols,
                          float* __restrict__ vals, int* __restrict__ cnt) {
    int row  = blockIdx.x * 4 + (threadIdx.x >> 6);
    int lane = threadIdx.x & 63;
    const float* rp = sup + (size_t)row * NN;
    int base = 0;
    for (int ch = 0; ch < NN / 64; ++ch) {
        float v = rp[ch * 64 + lane];
        unsigned long long m = __ballot(v != 0.0f);
        int pos = __popcll(m & ((1ull << lane) - 1ull));
        if (v != 0.0f) {
            int idx = base + pos;
            if (idx < MAXNNZ) {
                cols[row * MAXNNZ + idx] = ch * 64 + lane;
                vals[row * MAXNNZ + idx] = v;
            }
        }
        base += __popcll(m);
    }
    int kcp = base < MAXNNZ ? ((base + 7) & ~7) : MAXNNZ;
    for (int idx = (base < MAXNNZ ? base : MAXNNZ) + lane; idx < kcp; idx += 64) {
        cols[row * MAXNNZ + idx] = 0;
        vals[row * MAXNNZ + idx] = 0.0f;
    }
    if (lane == 0) cnt[row] = kcp;
}

// ---------------------------------------------------------------------------
// K2: build Xall (N x 4096) bf16 in packed column order.
//   cols [0,2048) = inputs, [2048,4096) = hx
// ---------------------------------------------------------------------------
__global__ void build_x0(const float* __restrict__ inp, const float* __restrict__ hxp,
                         unsigned short* __restrict__ Xall) {
    size_t tt = (size_t)blockIdx.x * 256 + threadIdx.x;
    size_t e  = tt * 4;
    int half  = e >= (size_t)8388608;
    size_t id = e & 8388607ull;               // b*262144 + n*64 + d
    const float* src = half ? hxp : inp;
    float4 f = *(const float4*)(src + id);
    int d = (int)(id & 63);                   // multiple of 4
    int n = (int)((id >> 6) & 4095);
    int b = (int)(id >> 18);
    int off = half * 2048 + (d >> 5) * 1024 + (b >> 4) * 512 + ((d >> 3) & 3) * 128 +
              (b & 15) * 8 + (d & 7);
    us4 o;
    o[0] = f2bf(f.x); o[1] = f2bf(f.y); o[2] = f2bf(f.z); o[3] = f2bf(f.w);
    *(us4*)(Xall + (size_t)n * 4096 + off) = o;
}

// ---------------------------------------------------------------------------
// K3: pack weights in per-lane fragment order for the A-operand (W as MFMA
// first arg): Wp[ct][kk][lane][e] = W[u = ct*16 + (lane&15)]
//                                    [k = kk*32 + (lane>>4)*8 + e]
// ---------------------------------------------------------------------------
__global__ void prep_w(const float* __restrict__ Wru, const float* __restrict__ Wc,
                       unsigned short* __restrict__ Wp1, unsigned short* __restrict__ Wp2) {
    int t = blockIdx.x * 256 + threadIdx.x;   // grid 288*256 = 73728 exactly
    int e  = t & 7;
    int li = (t >> 3) & 63;
    int lr = li & 15, kg = li >> 4;
    if (t < 49152) {
        int q = t >> 9;                        // ct*12 + kk, 0..95
        int ct = q / 12, kk = q - ct * 12;
        int u = ct * 16 + lr;
        int k = kk * 32 + kg * 8 + e;
        int s = k & 127, m = k >> 7;
        Wp1[t] = f2bf(Wru[(s * 3 + m) * 128 + u]);
    } else {
        int tt = t - 49152;                    // < 24576
        int q = tt >> 9;                       // 0..47
        int ct = q / 12, kk = q - ct * 12;
        int u = ct * 16 + lr;
        int k = kk * 32 + kg * 8 + e;
        int s = k & 127, m = k >> 7;
        Wp2[tt] = f2bf(Wc[(s * 3 + m) * 64 + u]);
    }
}

// ---------------------------------------------------------------------------
// SpMM: Y[row, c] = sum_k vals[row,k] * X[cols[row,k], c]   (column-agnostic)
// CHEB: Y = 2*(L@X) - Z0
// One wave per (row, 256-col chunk); 4 cols/lane (8B gathers). Per-XCD X
// working set = 256 cols x 4096 rows x 2B = 2 MB (half the XCD L2) -> no
// thrash against the Y/Z0 streams. Depth-8 rolling pipeline (8B buffers =
// 16 VGPR) covers ~2x the L2 latency of round 8's depth-4.
// ---------------------------------------------------------------------------
template <bool CHEB, int NCOLS>
__launch_bounds__(256, 6)
__global__ void spmm_kernel(const int* __restrict__ cols, const float* __restrict__ vals,
                            const int* __restrict__ cnt, const unsigned short* __restrict__ X,
                            const unsigned short* __restrict__ Z0,
                            unsigned short* __restrict__ Y) {
    int T = gridDim.x;
    int fid = blockIdx.x;
    int v = (fid & 7) * (T >> 3) + (fid >> 3);   // XCD k owns v in [k*T/8,(k+1)*T/8)
    int chunk = v >> 10;                          // 1024 row-groups per chunk
    int rg = v & 1023;
    int row = __builtin_amdgcn_readfirstlane(rg * 4 + (threadIdx.x >> 6));
    int lane = threadIdx.x & 63;
    int c = chunk * 256 + lane * 4;
    const int* cp = cols + row * MAXNNZ;
    const float* vp = vals + row * MAXNNZ;
    const int kc = cnt[row];                      // multiple of 8 (or 0)
    f32x2 acc0 = {0.f, 0.f}, acc1 = {0.f, 0.f};

    us4 zreg;
    if (CHEB) zreg = __builtin_nontemporal_load((const us4*)(Z0 + (size_t)row * NCOLS + c));

#define LD(K) (*(const us4*)(X + (size_t)cp[K] * NCOLS + c))
#define FMA1(BV, SV)                                                         \
    {                                                                        \
        f32x2 w = {SV, SV};                                                  \
        const unsigned* p = (const unsigned*)&BV;                            \
        f32x2 xv;                                                            \
        xv.x = __uint_as_float(p[0] << 16);                                  \
        xv.y = __uint_as_float(p[0] & 0xffff0000u);                          \
        acc0 = __builtin_elementwise_fma(w, xv, acc0);                       \
        xv.x = __uint_as_float(p[1] << 16);                                  \
        xv.y = __uint_as_float(p[1] & 0xffff0000u);                          \
        acc1 = __builtin_elementwise_fma(w, xv, acc1);                       \
    }

    if (kc) {
        us4 b0 = LD(0), b1 = LD(1), b2 = LD(2), b3 = LD(3);
        us4 b4 = LD(4), b5 = LD(5), b6 = LD(6), b7 = LD(7);
        float s0 = vp[0], s1 = vp[1], s2 = vp[2], s3 = vp[3];
        float s4 = vp[4], s5 = vp[5], s6 = vp[6], s7 = vp[7];
        int k = 0;
        for (; k + 16 <= kc; k += 8) {
            FMA1(b0, s0); b0 = LD(k + 8);  s0 = vp[k + 8];
            FMA1(b1, s1); b1 = LD(k + 9);  s1 = vp[k + 9];
            FMA1(b2, s2); b2 = LD(k + 10); s2 = vp[k + 10];
            FMA1(b3, s3); b3 = LD(k + 11); s3 = vp[k + 11];
            FMA1(b4, s4); b4 = LD(k + 12); s4 = vp[k + 12];
            FMA1(b5, s5); b5 = LD(k + 13); s5 = vp[k + 13];
            FMA1(b6, s6); b6 = LD(k + 14); s6 = vp[k + 14];
            FMA1(b7, s7); b7 = LD(k + 15); s7 = vp[k + 15];
        }
        FMA1(b0, s0); FMA1(b1, s1); FMA1(b2, s2); FMA1(b3, s3);
        FMA1(b4, s4); FMA1(b5, s5); FMA1(b6, s6); FMA1(b7, s7);
    }
#undef LD
#undef FMA1

    float a[4] = {acc0.x, acc0.y, acc1.x, acc1.y};
    if (CHEB) {
        const unsigned* pz = (const unsigned*)&zreg;
#pragma unroll
        for (int i = 0; i < 2; ++i) {
            a[2 * i]     = 2.f * a[2 * i]     - __uint_as_float(pz[i] << 16);
            a[2 * i + 1] = 2.f * a[2 * i + 1] - __uint_as_float(pz[i] & 0xffff0000u);
        }
    }
    us4 o;
#pragma unroll
    for (int i = 0; i < 4; ++i) o[i] = f2bf(a[i]);
    __builtin_nontemporal_store(o, (us4*)(Y + (size_t)row * NCOLS + c));
}

// ---------------------------------------------------------------------------
// Feature GEMM v6 (unchanged): W staged ONCE to LDS (48KB, fragment-packed,
// lane-linear ds_read_b128); A read directly from global in packed fragment
// order. No barriers in the k-loop. MFMA operands swapped so D rows = output
// col, D cols = batch -> contiguous epilogue accesses.
// ---------------------------------------------------------------------------
template <int MODE>
__launch_bounds__(512, 6)
__global__ void gemm_kernel(
    const unsigned short* __restrict__ baseIn, size_t bufIn, int rowIn,
    const unsigned short* __restrict__ baseSt, size_t bufSt, int rowSt,
    const unsigned short* __restrict__ Wp, const float* __restrict__ bias,
    const float* __restrict__ hx, unsigned short* __restrict__ ubuf,
    unsigned short* __restrict__ x2st, float* __restrict__ outp) {
    __shared__ __align__(16) unsigned short Wl[24576];  // 48 KB
    const int t = threadIdx.x;
    const int w = t >> 6, l = t & 63;
    const int bid = blockIdx.x;
    int h, ng;
    if (MODE == 0) { h = (bid >> 3) & 1; ng = (bid & 7) | ((bid >> 4) << 3); }
    else           { h = 0;             ng = bid; }
    const unsigned short* wsrc = Wp + (MODE == 0 ? h * 24576 : 0);
#pragma unroll
    for (int i = 0; i < 6; ++i) {
        int idx = i * 512 + t;
        *(us8*)(&Wl[idx * 8]) = *(const us8*)(wsrc + idx * 8);
    }
    __syncthreads();

    const int n = ng * 8 + w;
    f32x4 acc[4][2];
#pragma unroll
    for (int ct = 0; ct < 4; ++ct)
#pragma unroll
        for (int g = 0; g < 2; ++g)
#pragma unroll
            for (int r2 = 0; r2 < 4; ++r2) acc[ct][g][r2] = 0.f;

    for (int si = 0; si < 6; ++si) {
        const unsigned short* s = (si & 1)
            ? baseSt + (size_t)(si >> 1) * bufSt + (size_t)n * rowSt
            : baseIn + (size_t)(si >> 1) * bufIn + (size_t)n * rowIn;
        us8 aB[4];
#pragma unroll
        for (int dg = 0; dg < 4; ++dg)        // dg = dwin*2 + g
            aB[dg] = *(const us8*)(s + dg * 512 + l * 8);
#pragma unroll
        for (int dwin = 0; dwin < 2; ++dwin) {
            const int kk = si * 2 + dwin;
            bf16x8 wf[4];
#pragma unroll
            for (int ct = 0; ct < 4; ++ct)
                wf[ct] = *(const bf16x8*)(&Wl[ct * 6144 + kk * 512 + l * 8]);
#pragma unroll
            for (int ct = 0; ct < 4; ++ct)
#pragma unroll
                for (int g = 0; g < 2; ++g)
                    acc[ct][g] = __builtin_amdgcn_mfma_f32_16x16x32_bf16(
                        wf[ct], (bf16x8)aB[dwin * 2 + g], acc[ct][g], 0, 0, 0);
        }
    }

    // epilogue: D row = u = ct*16 + kg*4 + rr, D col = b = g*16 + lr
    const int kg = l >> 4, lr = l & 15;
#pragma unroll
    for (int ct = 0; ct < 4; ++ct) {
        const int u0 = ct * 16 + kg * 4;
        const int pofs = (ct >> 1) * 1024 + ((ct & 1) * 2 + (kg >> 1)) * 128 +
                         lr * 8 + (kg & 1) * 4;
#pragma unroll
        for (int g = 0; g < 2; ++g) {
            const int b = g * 16 + lr;
            if (MODE == 0) {
                if (h == 0) {  // r-gate -> r*h, packed
                    float4 hv = *(const float4*)(hx + (size_t)b * (NN * UU) +
                                                 (size_t)n * UU + u0);
                    us4 o;
#pragma unroll
                    for (int rr = 0; rr < 4; ++rr) {
                        float vv = acc[ct][g][rr] + bias[u0 + rr];
                        float sg = 1.f / (1.f + __expf(-vv));
                        o[rr] = f2bf(sg * ((const float*)&hv)[rr]);
                    }
                    *(us4*)(x2st + (size_t)n * 2048 + g * 512 + pofs) = o;
                } else {       // u-gate -> ubuf, packed
                    us4 o;
#pragma unroll
                    for (int rr = 0; rr < 4; ++rr) {
                        float vv = acc[ct][g][rr] + bias[64 + u0 + rr];
                        float sg = 1.f / (1.f + __expf(-vv));
                        o[rr] = f2bf(sg);
                    }
                    *(us4*)(ubuf + (size_t)n * 2048 + g * 512 + pofs) = o;
                }
            } else {
                float4 hv = *(const float4*)(hx + (size_t)b * (NN * UU) +
                                             (size_t)n * UU + u0);
                us4 uv = *(const us4*)(ubuf + (size_t)n * 2048 + g * 512 + pofs);
                float4 o;
#pragma unroll
                for (int rr = 0; rr < 4; ++rr) {
                    float vv = acc[ct][g][rr] + bias[u0 + rr];
                    float e2 = __expf(2.f * vv);
                    float cc = 1.f - 2.f / (e2 + 1.f);
                    float uu = bf2f(uv[rr]);
                    ((float*)&o)[rr] = uu * ((const float*)&hv)[rr] + (1.f - uu) * cc;
                }
                *(float4*)(outp + (size_t)b * (NN * UU) + (size_t)n * UU + u0) = o;
            }
        }
    }
}

// ---------------------------------------------------------------------------
extern "C" void kernel_launch(void* const* d_in, const int* in_sizes, int n_in,
                              void* d_out, int out_size, void* d_ws, size_t ws_size,
                              hipStream_t stream) {
    const float* inputs  = (const float*)d_in[0];
    const float* hx      = (const float*)d_in[1];
    const float* support = (const float*)d_in[2];
    const float* W_ru    = (const float*)d_in[3];
    const float* b_ru    = (const float*)d_in[4];
    const float* W_c     = (const float*)d_in[5];
    const float* b_c     = (const float*)d_in[6];
    float* out = (float*)d_out;

    char* ws = (char*)d_ws;
    size_t off = 0;
    auto alloc = [&](size_t bytes) -> char* {
        char* p = ws + off;
        off = (off + bytes + 255) & ~(size_t)255;
        return p;
    };
    const size_t BIG = (size_t)NN * 4096;   // elems per wide buffer
    const size_t SML = (size_t)NN * 2048;
    int*            colsI = (int*)  alloc((size_t)NN * MAXNNZ * 4);
    float*          valsF = (float*)alloc((size_t)NN * MAXNNZ * 4);
    int*            cntI  = (int*)  alloc((size_t)NN * 4);
    unsigned short* Wp1   = (unsigned short*)alloc(49152 * 2);
    unsigned short* Wp2   = (unsigned short*)alloc(24576 * 2);
    unsigned short* bufA  = (unsigned short*)alloc(3 * BIG * 2);  // Xall,Z1,Z2
    unsigned short* bufB  = (unsigned short*)alloc(3 * SML * 2);  // X2st,Z1st,Z2st
    unsigned short* ubuf  = (unsigned short*)alloc(SML * 2);
    if (off > ws_size) return;  // workspace too small -> loud validation failure

    unsigned short* Xall = bufA;
    unsigned short* Z1   = bufA + BIG;
    unsigned short* Z2   = bufA + 2 * BIG;
    unsigned short* X2st = bufB;
    unsigned short* Z1st = bufB + SML;
    unsigned short* Z2st = bufB + 2 * SML;

    build_ell<<<1024, 256, 0, stream>>>(support, colsI, valsF, cntI);
    build_x0<<<16384, 256, 0, stream>>>(inputs, hx, Xall);
    prep_w<<<288, 256, 0, stream>>>(W_ru, W_c, Wp1, Wp2);

    // gconv1 diffusion over all 4096 columns (16 chunks of 256)
    spmm_kernel<false, 4096><<<16384, 256, 0, stream>>>(colsI, valsF, cntI, Xall, Xall, Z1);
    spmm_kernel<true, 4096><<<16384, 256, 0, stream>>>(colsI, valsF, cntI, Z1, Xall, Z2);
    // gate GEMM -> r*h (X2st, packed) and u (ubuf, packed)
    gemm_kernel<0><<<1024, 512, 0, stream>>>(Xall, BIG, 4096, Xall + 2048, BIG, 4096,
                                             Wp1, b_ru, hx, ubuf, X2st, nullptr);
    // gconv2 diffusion: only the 2048 state columns (8 chunks of 256)
    spmm_kernel<false, 2048><<<8192, 256, 0, stream>>>(colsI, valsF, cntI, X2st, X2st, Z1st);
    spmm_kernel<true, 2048><<<8192, 256, 0, stream>>>(colsI, valsF, cntI, Z1st, X2st, Z2st);
    // candidate GEMM + GRU combine -> out
    gemm_kernel<1><<<512, 512, 0, stream>>>(Xall, BIG, 4096, X2st, SML, 2048,
                                            Wp2, b_c, hx, ubuf, nullptr, out);
}

// Round 10
// 283.894 us; speedup vs baseline: 1.2450x; 1.2450x over previous
//
#include <hip/hip_runtime.h>

#define NN 4096
#define BB 32
#define UU 64
#define MAXNNZ 96

typedef float f32x4 __attribute__((ext_vector_type(4)));
typedef float f32x2 __attribute__((ext_vector_type(2)));
typedef short bf16x8 __attribute__((ext_vector_type(8)));
typedef unsigned short us8 __attribute__((ext_vector_type(8)));
typedef unsigned short us4 __attribute__((ext_vector_type(4)));

__device__ __forceinline__ float bf2f(unsigned short u) {
    return __uint_as_float(((unsigned)u) << 16);
}
__device__ __forceinline__ unsigned short f2bf(float f) {
    unsigned x = __float_as_uint(f);
    x += 0x7fffu + ((x >> 16) & 1u);
    return (unsigned short)(x >> 16);
}

// Packed column order within each 2048-wide src (b in 0..31, d in 0..63):
//   off(b,d) = (d>>5)*1024 + (b>>4)*512 + ((d>>3)&3)*128 + (b&15)*8 + (d&7)
// i.e. [dwin][g][kg][lr][e] -- exactly the MFMA B-fragment load order.

// ---------------------------------------------------------------------------
// K1: dense support (4096x4096 f32) -> padded ELL (cols int32, vals f32, cnt)
// Rows padded with (col=0, val=0) to a multiple of 8 (pad gathers are L2-hot
// row 0, fma x0 = no-op) so the SpMM pipeline loop is branch-free.
// ---------------------------------------------------------------------------
__global__ void build_ell(const float* __restrict__ sup, int* __restrict__ cols,
                          float* __restrict__ vals, int* __restrict__ cnt) {
    int row  = blockIdx.x * 4 + (threadIdx.x >> 6);
    int lane = threadIdx.x & 63;
    const float* rp = sup + (size_t)row * NN;
    int base = 0;
    for (int ch = 0; ch < NN / 64; ++ch) {
        float v = rp[ch * 64 + lane];
        unsigned long long m = __ballot(v != 0.0f);
        int pos = __popcll(m & ((1ull << lane) - 1ull));
        if (v != 0.0f) {
            int idx = base + pos;
            if (idx < MAXNNZ) {
                cols[row * MAXNNZ + idx] = ch * 64 + lane;
                vals[row * MAXNNZ + idx] = v;
            }
        }
        base += __popcll(m);
    }
    int kcp = base < MAXNNZ ? ((base + 7) & ~7) : MAXNNZ;
    for (int idx = (base < MAXNNZ ? base : MAXNNZ) + lane; idx < kcp; idx += 64) {
        cols[row * MAXNNZ + idx] = 0;
        vals[row * MAXNNZ + idx] = 0.0f;
    }
    if (lane == 0) cnt[row] = kcp;
}

// ---------------------------------------------------------------------------
// K2: build Xall (N x 4096) bf16 in packed column order.
//   cols [0,2048) = inputs, [2048,4096) = hx
// ---------------------------------------------------------------------------
__global__ void build_x0(const float* __restrict__ inp, const float* __restrict__ hxp,
                         unsigned short* __restrict__ Xall) {
    size_t tt = (size_t)blockIdx.x * 256 + threadIdx.x;
    size_t e  = tt * 4;
    int half  = e >= (size_t)8388608;
    size_t id = e & 8388607ull;               // b*262144 + n*64 + d
    const float* src = half ? hxp : inp;
    float4 f = *(const float4*)(src + id);
    int d = (int)(id & 63);                   // multiple of 4
    int n = (int)((id >> 6) & 4095);
    int b = (int)(id >> 18);
    int off = half * 2048 + (d >> 5) * 1024 + (b >> 4) * 512 + ((d >> 3) & 3) * 128 +
              (b & 15) * 8 + (d & 7);
    us4 o;
    o[0] = f2bf(f.x); o[1] = f2bf(f.y); o[2] = f2bf(f.z); o[3] = f2bf(f.w);
    *(us4*)(Xall + (size_t)n * 4096 + off) = o;
}

// ---------------------------------------------------------------------------
// K3: pack weights in per-lane fragment order for the A-operand (W as MFMA
// first arg): Wp[ct][kk][lane][e] = W[u = ct*16 + (lane&15)]
//                                    [k = kk*32 + (lane>>4)*8 + e]
// ---------------------------------------------------------------------------
__global__ void prep_w(const float* __restrict__ Wru, const float* __restrict__ Wc,
                       unsigned short* __restrict__ Wp1, unsigned short* __restrict__ Wp2) {
    int t = blockIdx.x * 256 + threadIdx.x;   // grid 288*256 = 73728 exactly
    int e  = t & 7;
    int li = (t >> 3) & 63;
    int lr = li & 15, kg = li >> 4;
    if (t < 49152) {
        int q = t >> 9;                        // ct*12 + kk, 0..95
        int ct = q / 12, kk = q - ct * 12;
        int u = ct * 16 + lr;
        int k = kk * 32 + kg * 8 + e;
        int s = k & 127, m = k >> 7;
        Wp1[t] = f2bf(Wru[(s * 3 + m) * 128 + u]);
    } else {
        int tt = t - 49152;                    // < 24576
        int q = tt >> 9;                       // 0..47
        int ct = q / 12, kk = q - ct * 12;
        int u = ct * 16 + lr;
        int k = kk * 32 + kg * 8 + e;
        int s = k & 127, m = k >> 7;
        Wp2[tt] = f2bf(Wc[(s * 3 + m) * 64 + u]);
    }
}

// ---------------------------------------------------------------------------
// SpMM: Y[row, c] = sum_k vals[row,k] * X[cols[row,k], c]   (column-agnostic)
// CHEB: Y = 2*(L@X) - Z0
// One wave per (row, 512-col chunk); 8 cols/lane (16B gathers, ISA-max width).
// Depth-8 ROLLING pipeline, static buffer names: each FMA waits only for the
// oldest load (staggered vmcnt(7)), 8 loads in flight, 32 VGPR of buffers.
// kc is a multiple of 8 -> preload-8 / drain-8 fits exactly, no tail.
// ---------------------------------------------------------------------------
template <bool CHEB, int NCOLS>
__launch_bounds__(256, 6)
__global__ void spmm_kernel(const int* __restrict__ cols, const float* __restrict__ vals,
                            const int* __restrict__ cnt, const unsigned short* __restrict__ X,
                            const unsigned short* __restrict__ Z0,
                            unsigned short* __restrict__ Y) {
    int T = gridDim.x;
    int fid = blockIdx.x;
    int v = (fid & 7) * (T >> 3) + (fid >> 3);   // XCD k owns v in [k*T/8,(k+1)*T/8)
    int chunk = v >> 10;                          // 1024 row-groups per chunk
    int rg = v & 1023;
    int row = __builtin_amdgcn_readfirstlane(rg * 4 + (threadIdx.x >> 6));
    int lane = threadIdx.x & 63;
    int c = chunk * 512 + lane * 8;
    const int* cp = cols + row * MAXNNZ;
    const float* vp = vals + row * MAXNNZ;
    const int kc = cnt[row];                      // multiple of 8 (or 0)
    f32x2 acc0 = {0.f, 0.f}, acc1 = {0.f, 0.f}, acc2 = {0.f, 0.f}, acc3 = {0.f, 0.f};

    us8 zreg;
    if (CHEB) zreg = __builtin_nontemporal_load((const us8*)(Z0 + (size_t)row * NCOLS + c));

#define LD(K) (*(const us8*)(X + (size_t)cp[K] * NCOLS + c))
#define FMA1(BV, SV)                                                         \
    {                                                                        \
        f32x2 w = {SV, SV};                                                  \
        const unsigned* p = (const unsigned*)&BV;                            \
        f32x2 xv;                                                            \
        xv.x = __uint_as_float(p[0] << 16);                                  \
        xv.y = __uint_as_float(p[0] & 0xffff0000u);                          \
        acc0 = __builtin_elementwise_fma(w, xv, acc0);                       \
        xv.x = __uint_as_float(p[1] << 16);                                  \
        xv.y = __uint_as_float(p[1] & 0xffff0000u);                          \
        acc1 = __builtin_elementwise_fma(w, xv, acc1);                       \
        xv.x = __uint_as_float(p[2] << 16);                                  \
        xv.y = __uint_as_float(p[2] & 0xffff0000u);                          \
        acc2 = __builtin_elementwise_fma(w, xv, acc2);                       \
        xv.x = __uint_as_float(p[3] << 16);                                  \
        xv.y = __uint_as_float(p[3] & 0xffff0000u);                          \
        acc3 = __builtin_elementwise_fma(w, xv, acc3);                       \
    }

    if (kc) {
        us8 b0 = LD(0), b1 = LD(1), b2 = LD(2), b3 = LD(3);
        us8 b4 = LD(4), b5 = LD(5), b6 = LD(6), b7 = LD(7);
        float s0 = vp[0], s1 = vp[1], s2 = vp[2], s3 = vp[3];
        float s4 = vp[4], s5 = vp[5], s6 = vp[6], s7 = vp[7];
        int k = 0;
        for (; k + 16 <= kc; k += 8) {
            FMA1(b0, s0); b0 = LD(k + 8);  s0 = vp[k + 8];
            FMA1(b1, s1); b1 = LD(k + 9);  s1 = vp[k + 9];
            FMA1(b2, s2); b2 = LD(k + 10); s2 = vp[k + 10];
            FMA1(b3, s3); b3 = LD(k + 11); s3 = vp[k + 11];
            FMA1(b4, s4); b4 = LD(k + 12); s4 = vp[k + 12];
            FMA1(b5, s5); b5 = LD(k + 13); s5 = vp[k + 13];
            FMA1(b6, s6); b6 = LD(k + 14); s6 = vp[k + 14];
            FMA1(b7, s7); b7 = LD(k + 15); s7 = vp[k + 15];
        }
        FMA1(b0, s0); FMA1(b1, s1); FMA1(b2, s2); FMA1(b3, s3);
        FMA1(b4, s4); FMA1(b5, s5); FMA1(b6, s6); FMA1(b7, s7);
    }
#undef LD
#undef FMA1

    float a[8] = {acc0.x, acc0.y, acc1.x, acc1.y, acc2.x, acc2.y, acc3.x, acc3.y};
    if (CHEB) {
        const unsigned* pz = (const unsigned*)&zreg;
#pragma unroll
        for (int i = 0; i < 4; ++i) {
            a[2 * i]     = 2.f * a[2 * i]     - __uint_as_float(pz[i] << 16);
            a[2 * i + 1] = 2.f * a[2 * i + 1] - __uint_as_float(pz[i] & 0xffff0000u);
        }
    }
    us8 o;
#pragma unroll
    for (int i = 0; i < 8; ++i) o[i] = f2bf(a[i]);
    __builtin_nontemporal_store(o, (us8*)(Y + (size_t)row * NCOLS + c));
}

// ---------------------------------------------------------------------------
// Feature GEMM: W staged ONCE to LDS (48KB, fragment-packed, lane-linear
// ds_read_b128); A read directly from global in packed fragment order. No
// barriers in the k-loop. MFMA operands swapped so D rows = output col,
// D cols = batch -> contiguous epilogue accesses.
// h is read from the PACKED bf16 state half of Xall (hpk, stride 4096) at the
// same g*512+pofs index as x2st/ubuf -- no f32 hx traffic.
// ---------------------------------------------------------------------------
template <int MODE>
__launch_bounds__(512, 6)
__global__ void gemm_kernel(
    const unsigned short* __restrict__ baseIn, size_t bufIn, int rowIn,
    const unsigned short* __restrict__ baseSt, size_t bufSt, int rowSt,
    const unsigned short* __restrict__ Wp, const float* __restrict__ bias,
    const unsigned short* __restrict__ hpk, unsigned short* __restrict__ ubuf,
    unsigned short* __restrict__ x2st, float* __restrict__ outp) {
    __shared__ __align__(16) unsigned short Wl[24576];  // 48 KB
    const int t = threadIdx.x;
    const int w = t >> 6, l = t & 63;
    const int bid = blockIdx.x;
    int h, ng;
    if (MODE == 0) { h = (bid >> 3) & 1; ng = (bid & 7) | ((bid >> 4) << 3); }
    else           { h = 0;             ng = bid; }
    const unsigned short* wsrc = Wp + (MODE == 0 ? h * 24576 : 0);
#pragma unroll
    for (int i = 0; i < 6; ++i) {
        int idx = i * 512 + t;
        *(us8*)(&Wl[idx * 8]) = *(const us8*)(wsrc + idx * 8);
    }
    __syncthreads();

    const int n = ng * 8 + w;
    f32x4 acc[4][2];
#pragma unroll
    for (int ct = 0; ct < 4; ++ct)
#pragma unroll
        for (int g = 0; g < 2; ++g)
#pragma unroll
            for (int r2 = 0; r2 < 4; ++r2) acc[ct][g][r2] = 0.f;

    for (int si = 0; si < 6; ++si) {
        const unsigned short* s = (si & 1)
            ? baseSt + (size_t)(si >> 1) * bufSt + (size_t)n * rowSt
            : baseIn + (size_t)(si >> 1) * bufIn + (size_t)n * rowIn;
        us8 aB[4];
#pragma unroll
        for (int dg = 0; dg < 4; ++dg)        // dg = dwin*2 + g
            aB[dg] = *(const us8*)(s + dg * 512 + l * 8);
#pragma unroll
        for (int dwin = 0; dwin < 2; ++dwin) {
            const int kk = si * 2 + dwin;
            bf16x8 wf[4];
#pragma unroll
            for (int ct = 0; ct < 4; ++ct)
                wf[ct] = *(const bf16x8*)(&Wl[ct * 6144 + kk * 512 + l * 8]);
#pragma unroll
            for (int ct = 0; ct < 4; ++ct)
#pragma unroll
                for (int g = 0; g < 2; ++g)
                    acc[ct][g] = __builtin_amdgcn_mfma_f32_16x16x32_bf16(
                        wf[ct], (bf16x8)aB[dwin * 2 + g], acc[ct][g], 0, 0, 0);
        }
    }

    // epilogue: D row = u = ct*16 + kg*4 + rr, D col = b = g*16 + lr
    const int kg = l >> 4, lr = l & 15;
#pragma unroll
    for (int ct = 0; ct < 4; ++ct) {
        const int u0 = ct * 16 + kg * 4;
        const int pofs = (ct >> 1) * 1024 + ((ct & 1) * 2 + (kg >> 1)) * 128 +
                         lr * 8 + (kg & 1) * 4;
#pragma unroll
        for (int g = 0; g < 2; ++g) {
            if (MODE == 0) {
                if (h == 0) {  // r-gate -> r*h, packed
                    us4 hv = *(const us4*)(hpk + (size_t)n * 4096 + g * 512 + pofs);
                    us4 o;
#pragma unroll
                    for (int rr = 0; rr < 4; ++rr) {
                        float vv = acc[ct][g][rr] + bias[u0 + rr];
                        float sg = 1.f / (1.f + __expf(-vv));
                        o[rr] = f2bf(sg * bf2f(hv[rr]));
                    }
                    *(us4*)(x2st + (size_t)n * 2048 + g * 512 + pofs) = o;
                } else {       // u-gate -> ubuf, packed
                    us4 o;
#pragma unroll
                    for (int rr = 0; rr < 4; ++rr) {
                        float vv = acc[ct][g][rr] + bias[64 + u0 + rr];
                        float sg = 1.f / (1.f + __expf(-vv));
                        o[rr] = f2bf(sg);
                    }
                    *(us4*)(ubuf + (size_t)n * 2048 + g * 512 + pofs) = o;
                }
            } else {
                const int b = g * 16 + lr;
                us4 hv = *(const us4*)(hpk + (size_t)n * 4096 + g * 512 + pofs);
                us4 uv = *(const us4*)(ubuf + (size_t)n * 2048 + g * 512 + pofs);
                float4 o;
#pragma unroll
                for (int rr = 0; rr < 4; ++rr) {
                    float vv = acc[ct][g][rr] + bias[u0 + rr];
                    float e2 = __expf(2.f * vv);
                    float cc = 1.f - 2.f / (e2 + 1.f);
                    float uu = bf2f(uv[rr]);
                    ((float*)&o)[rr] = uu * bf2f(hv[rr]) + (1.f - uu) * cc;
                }
                *(float4*)(outp + (size_t)b * (NN * UU) + (size_t)n * UU + u0) = o;
            }
        }
    }
}

// ---------------------------------------------------------------------------
extern "C" void kernel_launch(void* const* d_in, const int* in_sizes, int n_in,
                              void* d_out, int out_size, void* d_ws, size_t ws_size,
                              hipStream_t stream) {
    const float* inputs  = (const float*)d_in[0];
    const float* hx      = (const float*)d_in[1];
    const float* support = (const float*)d_in[2];
    const float* W_ru    = (const float*)d_in[3];
    const float* b_ru    = (const float*)d_in[4];
    const float* W_c     = (const float*)d_in[5];
    const float* b_c     = (const float*)d_in[6];
    float* out = (float*)d_out;

    char* ws = (char*)d_ws;
    size_t off = 0;
    auto alloc = [&](size_t bytes) -> char* {
        char* p = ws + off;
        off = (off + bytes + 255) & ~(size_t)255;
        return p;
    };
    const size_t BIG = (size_t)NN * 4096;   // elems per wide buffer
    const size_t SML = (size_t)NN * 2048;
    int*            colsI = (int*)  alloc((size_t)NN * MAXNNZ * 4);
    float*          valsF = (float*)alloc((size_t)NN * MAXNNZ * 4);
    int*            cntI  = (int*)  alloc((size_t)NN * 4);
    unsigned short* Wp1   = (unsigned short*)alloc(49152 * 2);
    unsigned short* Wp2   = (unsigned short*)alloc(24576 * 2);
    unsigned short* bufA  = (unsigned short*)alloc(3 * BIG * 2);  // Xall,Z1,Z2
    unsigned short* bufB  = (unsigned short*)alloc(3 * SML * 2);  // X2st,Z1st,Z2st
    unsigned short* ubuf  = (unsigned short*)alloc(SML * 2);
    if (off > ws_size) return;  // workspace too small -> loud validation failure

    unsigned short* Xall = bufA;
    unsigned short* Z1   = bufA + BIG;
    unsigned short* Z2   = bufA + 2 * BIG;
    unsigned short* X2st = bufB;
    unsigned short* Z1st = bufB + SML;
    unsigned short* Z2st = bufB + 2 * SML;
    unsigned short* Hpk  = Xall + 2048;     // packed bf16 h (state half), stride 4096

    build_ell<<<1024, 256, 0, stream>>>(support, colsI, valsF, cntI);
    build_x0<<<16384, 256, 0, stream>>>(inputs, hx, Xall);
    prep_w<<<288, 256, 0, stream>>>(W_ru, W_c, Wp1, Wp2);

    // gconv1 diffusion over all 4096 columns (8 chunks of 512)
    spmm_kernel<false, 4096><<<8192, 256, 0, stream>>>(colsI, valsF, cntI, Xall, Xall, Z1);
    spmm_kernel<true, 4096><<<8192, 256, 0, stream>>>(colsI, valsF, cntI, Z1, Xall, Z2);
    // gate GEMM -> r*h (X2st, packed) and u (ubuf, packed)
    gemm_kernel<0><<<1024, 512, 0, stream>>>(Xall, BIG, 4096, Xall + 2048, BIG, 4096,
                                             Wp1, b_ru, Hpk, ubuf, X2st, nullptr);
    // gconv2 diffusion: only the 2048 state columns (4 chunks of 512)
    spmm_kernel<false, 2048><<<4096, 256, 0, stream>>>(colsI, valsF, cntI, X2st, X2st, Z1st);
    spmm_kernel<true, 2048><<<4096, 256, 0, stream>>>(colsI, valsF, cntI, Z1st, X2st, Z2st);
    // candidate GEMM + GRU combine -> out
    gemm_kernel<1><<<512, 512, 0, stream>>>(Xall, BIG, 4096, X2st, SML, 2048,
                                            Wp2, b_c, Hpk, ubuf, nullptr, out);
}

// Round 11
// 273.262 us; speedup vs baseline: 1.2934x; 1.0389x over previous
//
#include <hip/hip_runtime.h>

#define NN 4096
#define BB 32
#define UU 64
#define MAXNNZ 96

typedef float f32x4 __attribute__((ext_vector_type(4)));
typedef float f32x2 __attribute__((ext_vector_type(2)));
typedef short bf16x8 __attribute__((ext_vector_type(8)));
typedef unsigned short us8 __attribute__((ext_vector_type(8)));
typedef unsigned short us4 __attribute__((ext_vector_type(4)));

__device__ __forceinline__ float bf2f(unsigned short u) {
    return __uint_as_float(((unsigned)u) << 16);
}
__device__ __forceinline__ unsigned short f2bf(float f) {
    unsigned x = __float_as_uint(f);
    x += 0x7fffu + ((x >> 16) & 1u);
    return (unsigned short)(x >> 16);
}

// Packed column order within each 2048-wide src (b in 0..31, d in 0..63):
//   off(b,d) = (d>>5)*1024 + (b>>4)*512 + ((d>>3)&3)*128 + (b&15)*8 + (d&7)
// i.e. [dwin][g][kg][lr][e] -- exactly the MFMA B-fragment load order.

// ---------------------------------------------------------------------------
// prep_all: fused builders (independent, grid-partitioned; longest first).
//   blocks [0, 1024):        build_ell  -- support -> padded ELL (pad to x4)
//   blocks [1024, 17408):    build_x0   -- inputs/hx -> packed bf16 Xall
//   blocks [17408, 17696):   prep_w     -- weights -> fragment-packed bf16
// ---------------------------------------------------------------------------
__global__ void prep_all(const float* __restrict__ sup, const float* __restrict__ inp,
                         const float* __restrict__ hxp, const float* __restrict__ Wru,
                         const float* __restrict__ Wc, int* __restrict__ cols,
                         float* __restrict__ vals, int* __restrict__ cnt,
                         unsigned short* __restrict__ Xall,
                         unsigned short* __restrict__ Wp1,
                         unsigned short* __restrict__ Wp2) {
    const int bid = blockIdx.x;
    if (bid < 1024) {
        // ---- build_ell: one wave per support row, ballot compaction ----
        int row  = bid * 4 + (threadIdx.x >> 6);
        int lane = threadIdx.x & 63;
        const float* rp = sup + (size_t)row * NN;
        int base = 0;
        for (int ch = 0; ch < NN / 64; ++ch) {
            float v = rp[ch * 64 + lane];
            unsigned long long m = __ballot(v != 0.0f);
            int pos = __popcll(m & ((1ull << lane) - 1ull));
            if (v != 0.0f) {
                int idx = base + pos;
                if (idx < MAXNNZ) {
                    cols[row * MAXNNZ + idx] = ch * 64 + lane;
                    vals[row * MAXNNZ + idx] = v;
                }
            }
            base += __popcll(m);
        }
        int kb  = base < MAXNNZ ? base : MAXNNZ;
        int kcp = base < MAXNNZ ? ((base + 3) & ~3) : MAXNNZ;  // pad to x4
        for (int idx = kb + lane; idx < kcp; idx += 64) {
            cols[row * MAXNNZ + idx] = 0;    // L2/L1-hot row 0, val 0 -> no-op
            vals[row * MAXNNZ + idx] = 0.0f;
        }
        if (lane == 0) cnt[row] = kcp;
    } else if (bid < 17408) {
        // ---- build_x0: f32 -> packed bf16 ----
        size_t tt = (size_t)(bid - 1024) * 256 + threadIdx.x;
        size_t e  = tt * 4;
        int half  = e >= (size_t)8388608;
        size_t id = e & 8388607ull;           // b*262144 + n*64 + d
        const float* src = half ? hxp : inp;
        float4 f = *(const float4*)(src + id);
        int d = (int)(id & 63);               // multiple of 4
        int n = (int)((id >> 6) & 4095);
        int b = (int)(id >> 18);
        int off = half * 2048 + (d >> 5) * 1024 + (b >> 4) * 512 +
                  ((d >> 3) & 3) * 128 + (b & 15) * 8 + (d & 7);
        us4 o;
        o[0] = f2bf(f.x); o[1] = f2bf(f.y); o[2] = f2bf(f.z); o[3] = f2bf(f.w);
        *(us4*)(Xall + (size_t)n * 4096 + off) = o;
    } else {
        // ---- prep_w: fragment-pack weights ----
        int t = (bid - 17408) * 256 + threadIdx.x;   // 288*256 = 73728 exactly
        int e  = t & 7;
        int li = (t >> 3) & 63;
        int lr = li & 15, kg = li >> 4;
        if (t < 49152) {
            int q = t >> 9;                    // ct*12 + kk, 0..95
            int ct = q / 12, kk = q - ct * 12;
            int u = ct * 16 + lr;
            int k = kk * 32 + kg * 8 + e;
            int s = k & 127, m = k >> 7;
            Wp1[t] = f2bf(Wru[(s * 3 + m) * 128 + u]);
        } else {
            int tt2 = t - 49152;               // < 24576
            int q = tt2 >> 9;                  // 0..47
            int ct = q / 12, kk = q - ct * 12;
            int u = ct * 16 + lr;
            int k = kk * 32 + kg * 8 + e;
            int s = k & 127, m = k >> 7;
            Wp2[tt2] = f2bf(Wc[(s * 3 + m) * 64 + u]);
        }
    }
}

// ---------------------------------------------------------------------------
// SpMM: Y[row, c] = sum_k vals[row,k] * X[cols[row,k], c]   (column-agnostic)
// CHEB: Y = 2*(L@X) - Z0
// One wave per (row, 512-col chunk); 8 cols/lane (16B gathers, ISA-max).
// Depth-4 rolling pipeline (r8-proven: VGPR 20, 60 us = ~90% of per-XCD pure
// L2 read BW at 2.2 TB/s/XCD -- the roofline for this gather pattern).
// kc is a multiple of 4 -> preload-4 / drain-4, no tail.
// ---------------------------------------------------------------------------
template <bool CHEB, int NCOLS>
__launch_bounds__(256, 6)
__global__ void spmm_kernel(const int* __restrict__ cols, const float* __restrict__ vals,
                            const int* __restrict__ cnt, const unsigned short* __restrict__ X,
                            const unsigned short* __restrict__ Z0,
                            unsigned short* __restrict__ Y) {
    int T = gridDim.x;
    int fid = blockIdx.x;
    int v = (fid & 7) * (T >> 3) + (fid >> 3);   // XCD k owns v in [k*T/8,(k+1)*T/8)
    int chunk = v >> 10;                          // 1024 row-groups per chunk
    int rg = v & 1023;
    int row = __builtin_amdgcn_readfirstlane(rg * 4 + (threadIdx.x >> 6));
    int lane = threadIdx.x & 63;
    int c = chunk * 512 + lane * 8;
    const int* cp = cols + row * MAXNNZ;
    const float* vp = vals + row * MAXNNZ;
    const int kc = cnt[row];                      // multiple of 4 (or 0)
    f32x2 acc0 = {0.f, 0.f}, acc1 = {0.f, 0.f}, acc2 = {0.f, 0.f}, acc3 = {0.f, 0.f};

    us8 zreg;
    if (CHEB) zreg = __builtin_nontemporal_load((const us8*)(Z0 + (size_t)row * NCOLS + c));

#define LD(K) (*(const us8*)(X + (size_t)cp[K] * NCOLS + c))
#define FMA1(BV, SV)                                                         \
    {                                                                        \
        f32x2 w = {SV, SV};                                                  \
        const unsigned* p = (const unsigned*)&BV;                            \
        f32x2 xv;                                                            \
        xv.x = __uint_as_float(p[0] << 16);                                  \
        xv.y = __uint_as_float(p[0] & 0xffff0000u);                          \
        acc0 = __builtin_elementwise_fma(w, xv, acc0);                       \
        xv.x = __uint_as_float(p[1] << 16);                                  \
        xv.y = __uint_as_float(p[1] & 0xffff0000u);                          \
        acc1 = __builtin_elementwise_fma(w, xv, acc1);                       \
        xv.x = __uint_as_float(p[2] << 16);                                  \
        xv.y = __uint_as_float(p[2] & 0xffff0000u);                          \
        acc2 = __builtin_elementwise_fma(w, xv, acc2);                       \
        xv.x = __uint_as_float(p[3] << 16);                                  \
        xv.y = __uint_as_float(p[3] & 0xffff0000u);                          \
        acc3 = __builtin_elementwise_fma(w, xv, acc3);                       \
    }

    if (kc) {
        us8 b0 = LD(0), b1 = LD(1), b2 = LD(2), b3 = LD(3);
        float s0 = vp[0], s1 = vp[1], s2 = vp[2], s3 = vp[3];
        int k = 0;
        for (; k + 8 <= kc; k += 4) {
            FMA1(b0, s0); b0 = LD(k + 4); s0 = vp[k + 4];
            FMA1(b1, s1); b1 = LD(k + 5); s1 = vp[k + 5];
            FMA1(b2, s2); b2 = LD(k + 6); s2 = vp[k + 6];
            FMA1(b3, s3); b3 = LD(k + 7); s3 = vp[k + 7];
        }
        FMA1(b0, s0); FMA1(b1, s1); FMA1(b2, s2); FMA1(b3, s3);
    }
#undef LD
#undef FMA1

    float a[8] = {acc0.x, acc0.y, acc1.x, acc1.y, acc2.x, acc2.y, acc3.x, acc3.y};
    if (CHEB) {
        const unsigned* pz = (const unsigned*)&zreg;
#pragma unroll
        for (int i = 0; i < 4; ++i) {
            a[2 * i]     = 2.f * a[2 * i]     - __uint_as_float(pz[i] << 16);
            a[2 * i + 1] = 2.f * a[2 * i + 1] - __uint_as_float(pz[i] & 0xffff0000u);
        }
    }
    us8 o;
#pragma unroll
    for (int i = 0; i < 8; ++i) o[i] = f2bf(a[i]);
    __builtin_nontemporal_store(o, (us8*)(Y + (size_t)row * NCOLS + c));
}

// ---------------------------------------------------------------------------
// Feature GEMM: W staged ONCE to LDS (48KB, fragment-packed, lane-linear
// ds_read_b128); A read directly from global in packed fragment order. No
// barriers in the k-loop. MFMA operands swapped so D rows = output col,
// D cols = batch -> contiguous epilogue accesses.
// h read from the PACKED bf16 state half of Xall (hpk, stride 4096).
// ---------------------------------------------------------------------------
template <int MODE>
__launch_bounds__(512, 6)
__global__ void gemm_kernel(
    const unsigned short* __restrict__ baseIn, size_t bufIn, int rowIn,
    const unsigned short* __restrict__ baseSt, size_t bufSt, int rowSt,
    const unsigned short* __restrict__ Wp, const float* __restrict__ bias,
    const unsigned short* __restrict__ hpk, unsigned short* __restrict__ ubuf,
    unsigned short* __restrict__ x2st, float* __restrict__ outp) {
    __shared__ __align__(16) unsigned short Wl[24576];  // 48 KB
    const int t = threadIdx.x;
    const int w = t >> 6, l = t & 63;
    const int bid = blockIdx.x;
    int h, ng;
    if (MODE == 0) { h = (bid >> 3) & 1; ng = (bid & 7) | ((bid >> 4) << 3); }
    else           { h = 0;             ng = bid; }
    const unsigned short* wsrc = Wp + (MODE == 0 ? h * 24576 : 0);
#pragma unroll
    for (int i = 0; i < 6; ++i) {
        int idx = i * 512 + t;
        *(us8*)(&Wl[idx * 8]) = *(const us8*)(wsrc + idx * 8);
    }
    __syncthreads();

    const int n = ng * 8 + w;
    f32x4 acc[4][2];
#pragma unroll
    for (int ct = 0; ct < 4; ++ct)
#pragma unroll
        for (int g = 0; g < 2; ++g)
#pragma unroll
            for (int r2 = 0; r2 < 4; ++r2) acc[ct][g][r2] = 0.f;

    for (int si = 0; si < 6; ++si) {
        const unsigned short* s = (si & 1)
            ? baseSt + (size_t)(si >> 1) * bufSt + (size_t)n * rowSt
            : baseIn + (size_t)(si >> 1) * bufIn + (size_t)n * rowIn;
        us8 aB[4];
#pragma unroll
        for (int dg = 0; dg < 4; ++dg)        // dg = dwin*2 + g
            aB[dg] = *(const us8*)(s + dg * 512 + l * 8);
#pragma unroll
        for (int dwin = 0; dwin < 2; ++dwin) {
            const int kk = si * 2 + dwin;
            bf16x8 wf[4];
#pragma unroll
            for (int ct = 0; ct < 4; ++ct)
                wf[ct] = *(const bf16x8*)(&Wl[ct * 6144 + kk * 512 + l * 8]);
#pragma unroll
            for (int ct = 0; ct < 4; ++ct)
#pragma unroll
                for (int g = 0; g < 2; ++g)
                    acc[ct][g] = __builtin_amdgcn_mfma_f32_16x16x32_bf16(
                        wf[ct], (bf16x8)aB[dwin * 2 + g], acc[ct][g], 0, 0, 0);
        }
    }

    // epilogue: D row = u = ct*16 + kg*4 + rr, D col = b = g*16 + lr
    const int kg = l >> 4, lr = l & 15;
#pragma unroll
    for (int ct = 0; ct < 4; ++ct) {
        const int u0 = ct * 16 + kg * 4;
        const int pofs = (ct >> 1) * 1024 + ((ct & 1) * 2 + (kg >> 1)) * 128 +
                         lr * 8 + (kg & 1) * 4;
#pragma unroll
        for (int g = 0; g < 2; ++g) {
            if (MODE == 0) {
                if (h == 0) {  // r-gate -> r*h, packed
                    us4 hv = *(const us4*)(hpk + (size_t)n * 4096 + g * 512 + pofs);
                    us4 o;
#pragma unroll
                    for (int rr = 0; rr < 4; ++rr) {
                        float vv = acc[ct][g][rr] + bias[u0 + rr];
                        float sg = 1.f / (1.f + __expf(-vv));
                        o[rr] = f2bf(sg * bf2f(hv[rr]));
                    }
                    *(us4*)(x2st + (size_t)n * 2048 + g * 512 + pofs) = o;
                } else {       // u-gate -> ubuf, packed
                    us4 o;
#pragma unroll
                    for (int rr = 0; rr < 4; ++rr) {
                        float vv = acc[ct][g][rr] + bias[64 + u0 + rr];
                        float sg = 1.f / (1.f + __expf(-vv));
                        o[rr] = f2bf(sg);
                    }
                    *(us4*)(ubuf + (size_t)n * 2048 + g * 512 + pofs) = o;
                }
            } else {
                const int b = g * 16 + lr;
                us4 hv = *(const us4*)(hpk + (size_t)n * 4096 + g * 512 + pofs);
                us4 uv = *(const us4*)(ubuf + (size_t)n * 2048 + g * 512 + pofs);
                float4 o;
#pragma unroll
                for (int rr = 0; rr < 4; ++rr) {
                    float vv = acc[ct][g][rr] + bias[u0 + rr];
                    float e2 = __expf(2.f * vv);
                    float cc = 1.f - 2.f / (e2 + 1.f);
                    float uu = bf2f(uv[rr]);
                    ((float*)&o)[rr] = uu * bf2f(hv[rr]) + (1.f - uu) * cc;
                }
                *(float4*)(outp + (size_t)b * (NN * UU) + (size_t)n * UU + u0) = o;
            }
        }
    }
}

// ---------------------------------------------------------------------------
extern "C" void kernel_launch(void* const* d_in, const int* in_sizes, int n_in,
                              void* d_out, int out_size, void* d_ws, size_t ws_size,
                              hipStream_t stream) {
    const float* inputs  = (const float*)d_in[0];
    const float* hx      = (const float*)d_in[1];
    const float* support = (const float*)d_in[2];
    const float* W_ru    = (const float*)d_in[3];
    const float* b_ru    = (const float*)d_in[4];
    const float* W_c     = (const float*)d_in[5];
    const float* b_c     = (const float*)d_in[6];
    float* out = (float*)d_out;

    char* ws = (char*)d_ws;
    size_t off = 0;
    auto alloc = [&](size_t bytes) -> char* {
        char* p = ws + off;
        off = (off + bytes + 255) & ~(size_t)255;
        return p;
    };
    const size_t BIG = (size_t)NN * 4096;   // elems per wide buffer
    const size_t SML = (size_t)NN * 2048;
    int*            colsI = (int*)  alloc((size_t)NN * MAXNNZ * 4);
    float*          valsF = (float*)alloc((size_t)NN * MAXNNZ * 4);
    int*            cntI  = (int*)  alloc((size_t)NN * 4);
    unsigned short* Wp1   = (unsigned short*)alloc(49152 * 2);
    unsigned short* Wp2   = (unsigned short*)alloc(24576 * 2);
    unsigned short* bufA  = (unsigned short*)alloc(3 * BIG * 2);  // Xall,Z1,Z2
    unsigned short* bufB  = (unsigned short*)alloc(3 * SML * 2);  // X2st,Z1st,Z2st
    unsigned short* ubuf  = (unsigned short*)alloc(SML * 2);
    if (off > ws_size) return;  // workspace too small -> loud validation failure

    unsigned short* Xall = bufA;
    unsigned short* Z1   = bufA + BIG;
    unsigned short* Z2   = bufA + 2 * BIG;
    unsigned short* X2st = bufB;
    unsigned short* Z1st = bufB + SML;
    unsigned short* Z2st = bufB + 2 * SML;
    unsigned short* Hpk  = Xall + 2048;     // packed bf16 h (state half), stride 4096

    // fused builders: ELL + packed X + packed W in one dispatch
    prep_all<<<17696, 256, 0, stream>>>(support, inputs, hx, W_ru, W_c,
                                        colsI, valsF, cntI, Xall, Wp1, Wp2);

    // gconv1 diffusion over all 4096 columns (8 chunks of 512)
    spmm_kernel<false, 4096><<<8192, 256, 0, stream>>>(colsI, valsF, cntI, Xall, Xall, Z1);
    spmm_kernel<true, 4096><<<8192, 256, 0, stream>>>(colsI, valsF, cntI, Z1, Xall, Z2);
    // gate GEMM -> r*h (X2st, packed) and u (ubuf, packed)
    gemm_kernel<0><<<1024, 512, 0, stream>>>(Xall, BIG, 4096, Xall + 2048, BIG, 4096,
                                             Wp1, b_ru, Hpk, ubuf, X2st, nullptr);
    // gconv2 diffusion: only the 2048 state columns (4 chunks of 512)
    spmm_kernel<false, 2048><<<4096, 256, 0, stream>>>(colsI, valsF, cntI, X2st, X2st, Z1st);
    spmm_kernel<true, 2048><<<4096, 256, 0, stream>>>(colsI, valsF, cntI, Z1st, X2st, Z2st);
    // candidate GEMM + GRU combine -> out
    gemm_kernel<1><<<512, 512, 0, stream>>>(Xall, BIG, 4096, X2st, SML, 2048,
                                            Wp2, b_c, Hpk, ubuf, nullptr, out);
}

// Round 12
// 258.818 us; speedup vs baseline: 1.3656x; 1.0558x over previous
//
#include <hip/hip_runtime.h>

#define NN 4096
#define BB 32
#define UU 64
#define MAXNNZ 96

typedef float f32x4 __attribute__((ext_vector_type(4)));
typedef float f32x2 __attribute__((ext_vector_type(2)));
typedef short bf16x8 __attribute__((ext_vector_type(8)));
typedef unsigned short us8 __attribute__((ext_vector_type(8)));
typedef unsigned short us4 __attribute__((ext_vector_type(4)));

__device__ __forceinline__ float bf2f(unsigned short u) {
    return __uint_as_float(((unsigned)u) << 16);
}
__device__ __forceinline__ unsigned short f2bf(float f) {
    unsigned x = __float_as_uint(f);
    x += 0x7fffu + ((x >> 16) & 1u);
    return (unsigned short)(x >> 16);
}

// Packed column order within each 2048-wide src (b in 0..31, d in 0..63):
//   off(b,d) = (d>>5)*1024 + (b>>4)*512 + ((d>>3)&3)*128 + (b&15)*8 + (d&7)
// i.e. [dwin][g][kg][lr][e] -- exactly the MFMA B-fragment load order.

// ---------------------------------------------------------------------------
// prep_all: fused builders (independent, grid-partitioned; longest first).
//   blocks [0, 4096):        build_ell  -- ONE BLOCK (4 waves) PER ROW:
//     wave w owns cols [w*1024,(w+1)*1024) in 16 VGPR-resident chunks
//     (independent loads -> pipelined; serial ballot chain 64 -> 16 iters),
//     4-entry LDS prefix combines waves; column order identical to the old
//     serial builder; rows padded with (0, 0.0) to a multiple of 4.
//   blocks [4096, 20480):    build_x0   -- inputs/hx -> packed bf16 Xall
//   blocks [20480, 20768):   prep_w     -- weights -> fragment-packed bf16
// ---------------------------------------------------------------------------
__global__ void prep_all(const float* __restrict__ sup, const float* __restrict__ inp,
                         const float* __restrict__ hxp, const float* __restrict__ Wru,
                         const float* __restrict__ Wc, int* __restrict__ cols,
                         float* __restrict__ vals, int* __restrict__ cnt,
                         unsigned short* __restrict__ Xall,
                         unsigned short* __restrict__ Wp1,
                         unsigned short* __restrict__ Wp2) {
    __shared__ int wtot[4];
    const int bid = blockIdx.x;
    if (bid < 4096) {
        // ---- build_ell: block = row, wave = 1024-col span ----
        const int w = threadIdx.x >> 6, lane = threadIdx.x & 63;
        const int row = bid;
        const float* rp = sup + (size_t)row * NN + w * 1024;
        float v[16];
#pragma unroll
        for (int i = 0; i < 16; ++i) v[i] = rp[i * 64 + lane];
        const unsigned long long lt = (1ull << lane) - 1ull;
        int base[16];
        int tot = 0;
#pragma unroll
        for (int i = 0; i < 16; ++i) {
            unsigned long long m = __ballot(v[i] != 0.0f);
            base[i] = tot;
            tot += __popcll(m);
        }
        if (lane == 0) wtot[w] = tot;
        __syncthreads();
        int wbase = 0, btot = 0;
#pragma unroll
        for (int j = 0; j < 4; ++j) {
            int tj = wtot[j];
            if (j < w) wbase += tj;
            btot += tj;
        }
#pragma unroll
        for (int i = 0; i < 16; ++i) {
            unsigned long long m = __ballot(v[i] != 0.0f);
            int pos = __popcll(m & lt);
            if (v[i] != 0.0f) {
                int idx = wbase + base[i] + pos;
                if (idx < MAXNNZ) {
                    cols[row * MAXNNZ + idx] = w * 1024 + i * 64 + lane;
                    vals[row * MAXNNZ + idx] = v[i];
                }
            }
        }
        int kb  = btot < MAXNNZ ? btot : MAXNNZ;
        int kcp = btot < MAXNNZ ? ((btot + 3) & ~3) : MAXNNZ;  // pad to x4
        if (w == 0) {
            for (int idx = kb + lane; idx < kcp; idx += 64) {
                cols[row * MAXNNZ + idx] = 0;   // L1/L2-hot row 0, val 0 -> no-op
                vals[row * MAXNNZ + idx] = 0.0f;
            }
            if (lane == 0) cnt[row] = kcp;
        }
    } else if (bid < 20480) {
        // ---- build_x0: f32 -> packed bf16 ----
        size_t tt = (size_t)(bid - 4096) * 256 + threadIdx.x;
        size_t e  = tt * 4;
        int half  = e >= (size_t)8388608;
        size_t id = e & 8388607ull;           // b*262144 + n*64 + d
        const float* src = half ? hxp : inp;
        float4 f = *(const float4*)(src + id);
        int d = (int)(id & 63);               // multiple of 4
        int n = (int)((id >> 6) & 4095);
        int b = (int)(id >> 18);
        int off = half * 2048 + (d >> 5) * 1024 + (b >> 4) * 512 +
                  ((d >> 3) & 3) * 128 + (b & 15) * 8 + (d & 7);
        us4 o;
        o[0] = f2bf(f.x); o[1] = f2bf(f.y); o[2] = f2bf(f.z); o[3] = f2bf(f.w);
        *(us4*)(Xall + (size_t)n * 4096 + off) = o;
    } else {
        // ---- prep_w: fragment-pack weights ----
        int t = (bid - 20480) * 256 + threadIdx.x;   // 288*256 = 73728 exactly
        int e  = t & 7;
        int li = (t >> 3) & 63;
        int lr = li & 15, kg = li >> 4;
        if (t < 49152) {
            int q = t >> 9;                    // ct*12 + kk, 0..95
            int ct = q / 12, kk = q - ct * 12;
            int u = ct * 16 + lr;
            int k = kk * 32 + kg * 8 + e;
            int s = k & 127, m = k >> 7;
            Wp1[t] = f2bf(Wru[(s * 3 + m) * 128 + u]);
        } else {
            int tt2 = t - 49152;               // < 24576
            int q = tt2 >> 9;                  // 0..47
            int ct = q / 12, kk = q - ct * 12;
            int u = ct * 16 + lr;
            int k = kk * 32 + kg * 8 + e;
            int s = k & 127, m = k >> 7;
            Wp2[tt2] = f2bf(Wc[(s * 3 + m) * 64 + u]);
        }
    }
}

// ---------------------------------------------------------------------------
// SpMM: Y[row, c] = sum_k vals[row,k] * X[cols[row,k], c]   (column-agnostic)
// CHEB: Y = 2*(L@X) - Z0
// One wave per (row, 512-col chunk); 8 cols/lane (16B gathers, ISA-max).
// Depth-4 rolling pipeline (r8-proven: VGPR 20, 60 us = ~90% of per-XCD pure
// L2 read BW at 2.2 TB/s/XCD -- the roofline for this gather pattern).
// kc is a multiple of 4 -> preload-4 / drain-4, no tail.
// ---------------------------------------------------------------------------
template <bool CHEB, int NCOLS>
__launch_bounds__(256, 6)
__global__ void spmm_kernel(const int* __restrict__ cols, const float* __restrict__ vals,
                            const int* __restrict__ cnt, const unsigned short* __restrict__ X,
                            const unsigned short* __restrict__ Z0,
                            unsigned short* __restrict__ Y) {
    int T = gridDim.x;
    int fid = blockIdx.x;
    int v = (fid & 7) * (T >> 3) + (fid >> 3);   // XCD k owns v in [k*T/8,(k+1)*T/8)
    int chunk = v >> 10;                          // 1024 row-groups per chunk
    int rg = v & 1023;
    int row = __builtin_amdgcn_readfirstlane(rg * 4 + (threadIdx.x >> 6));
    int lane = threadIdx.x & 63;
    int c = chunk * 512 + lane * 8;
    const int* cp = cols + row * MAXNNZ;
    const float* vp = vals + row * MAXNNZ;
    const int kc = cnt[row];                      // multiple of 4 (or 0)
    f32x2 acc0 = {0.f, 0.f}, acc1 = {0.f, 0.f}, acc2 = {0.f, 0.f}, acc3 = {0.f, 0.f};

    us8 zreg;
    if (CHEB) zreg = __builtin_nontemporal_load((const us8*)(Z0 + (size_t)row * NCOLS + c));

#define LD(K) (*(const us8*)(X + (size_t)cp[K] * NCOLS + c))
#define FMA1(BV, SV)                                                         \
    {                                                                        \
        f32x2 w = {SV, SV};                                                  \
        const unsigned* p = (const unsigned*)&BV;                            \
        f32x2 xv;                                                            \
        xv.x = __uint_as_float(p[0] << 16);                                  \
        xv.y = __uint_as_float(p[0] & 0xffff0000u);                          \
        acc0 = __builtin_elementwise_fma(w, xv, acc0);                       \
        xv.x = __uint_as_float(p[1] << 16);                                  \
        xv.y = __uint_as_float(p[1] & 0xffff0000u);                          \
        acc1 = __builtin_elementwise_fma(w, xv, acc1);                       \
        xv.x = __uint_as_float(p[2] << 16);                                  \
        xv.y = __uint_as_float(p[2] & 0xffff0000u);                          \
        acc2 = __builtin_elementwise_fma(w, xv, acc2);                       \
        xv.x = __uint_as_float(p[3] << 16);                                  \
        xv.y = __uint_as_float(p[3] & 0xffff0000u);                          \
        acc3 = __builtin_elementwise_fma(w, xv, acc3);                       \
    }

    if (kc) {
        us8 b0 = LD(0), b1 = LD(1), b2 = LD(2), b3 = LD(3);
        float s0 = vp[0], s1 = vp[1], s2 = vp[2], s3 = vp[3];
        int k = 0;
        for (; k + 8 <= kc; k += 4) {
            FMA1(b0, s0); b0 = LD(k + 4); s0 = vp[k + 4];
            FMA1(b1, s1); b1 = LD(k + 5); s1 = vp[k + 5];
            FMA1(b2, s2); b2 = LD(k + 6); s2 = vp[k + 6];
            FMA1(b3, s3); b3 = LD(k + 7); s3 = vp[k + 7];
        }
        FMA1(b0, s0); FMA1(b1, s1); FMA1(b2, s2); FMA1(b3, s3);
    }
#undef LD
#undef FMA1

    float a[8] = {acc0.x, acc0.y, acc1.x, acc1.y, acc2.x, acc2.y, acc3.x, acc3.y};
    if (CHEB) {
        const unsigned* pz = (const unsigned*)&zreg;
#pragma unroll
        for (int i = 0; i < 4; ++i) {
            a[2 * i]     = 2.f * a[2 * i]     - __uint_as_float(pz[i] << 16);
            a[2 * i + 1] = 2.f * a[2 * i + 1] - __uint_as_float(pz[i] & 0xffff0000u);
        }
    }
    us8 o;
#pragma unroll
    for (int i = 0; i < 8; ++i) o[i] = f2bf(a[i]);
    __builtin_nontemporal_store(o, (us8*)(Y + (size_t)row * NCOLS + c));
}

// ---------------------------------------------------------------------------
// Feature GEMM: W staged ONCE to LDS (48KB, fragment-packed, lane-linear
// ds_read_b128); A read directly from global in packed fragment order. No
// barriers in the k-loop. MFMA operands swapped so D rows = output col,
// D cols = batch -> contiguous epilogue accesses.
// h read from the PACKED bf16 state half of Xall (hpk, stride 4096).
// ---------------------------------------------------------------------------
template <int MODE>
__launch_bounds__(512, 6)
__global__ void gemm_kernel(
    const unsigned short* __restrict__ baseIn, size_t bufIn, int rowIn,
    const unsigned short* __restrict__ baseSt, size_t bufSt, int rowSt,
    const unsigned short* __restrict__ Wp, const float* __restrict__ bias,
    const unsigned short* __restrict__ hpk, unsigned short* __restrict__ ubuf,
    unsigned short* __restrict__ x2st, float* __restrict__ outp) {
    __shared__ __align__(16) unsigned short Wl[24576];  // 48 KB
    const int t = threadIdx.x;
    const int w = t >> 6, l = t & 63;
    const int bid = blockIdx.x;
    int h, ng;
    if (MODE == 0) { h = (bid >> 3) & 1; ng = (bid & 7) | ((bid >> 4) << 3); }
    else           { h = 0;             ng = bid; }
    const unsigned short* wsrc = Wp + (MODE == 0 ? h * 24576 : 0);
#pragma unroll
    for (int i = 0; i < 6; ++i) {
        int idx = i * 512 + t;
        *(us8*)(&Wl[idx * 8]) = *(const us8*)(wsrc + idx * 8);
    }
    __syncthreads();

    const int n = ng * 8 + w;
    f32x4 acc[4][2];
#pragma unroll
    for (int ct = 0; ct < 4; ++ct)
#pragma unroll
        for (int g = 0; g < 2; ++g)
#pragma unroll
            for (int r2 = 0; r2 < 4; ++r2) acc[ct][g][r2] = 0.f;

    for (int si = 0; si < 6; ++si) {
        const unsigned short* s = (si & 1)
            ? baseSt + (size_t)(si >> 1) * bufSt + (size_t)n * rowSt
            : baseIn + (size_t)(si >> 1) * bufIn + (size_t)n * rowIn;
        us8 aB[4];
#pragma unroll
        for (int dg = 0; dg < 4; ++dg)        // dg = dwin*2 + g
            aB[dg] = *(const us8*)(s + dg * 512 + l * 8);
#pragma unroll
        for (int dwin = 0; dwin < 2; ++dwin) {
            const int kk = si * 2 + dwin;
            bf16x8 wf[4];
#pragma unroll
            for (int ct = 0; ct < 4; ++ct)
                wf[ct] = *(const bf16x8*)(&Wl[ct * 6144 + kk * 512 + l * 8]);
#pragma unroll
            for (int ct = 0; ct < 4; ++ct)
#pragma unroll
                for (int g = 0; g < 2; ++g)
                    acc[ct][g] = __builtin_amdgcn_mfma_f32_16x16x32_bf16(
                        wf[ct], (bf16x8)aB[dwin * 2 + g], acc[ct][g], 0, 0, 0);
        }
    }

    // epilogue: D row = u = ct*16 + kg*4 + rr, D col = b = g*16 + lr
    const int kg = l >> 4, lr = l & 15;
#pragma unroll
    for (int ct = 0; ct < 4; ++ct) {
        const int u0 = ct * 16 + kg * 4;
        const int pofs = (ct >> 1) * 1024 + ((ct & 1) * 2 + (kg >> 1)) * 128 +
                         lr * 8 + (kg & 1) * 4;
#pragma unroll
        for (int g = 0; g < 2; ++g) {
            if (MODE == 0) {
                if (h == 0) {  // r-gate -> r*h, packed
                    us4 hv = *(const us4*)(hpk + (size_t)n * 4096 + g * 512 + pofs);
                    us4 o;
#pragma unroll
                    for (int rr = 0; rr < 4; ++rr) {
                        float vv = acc[ct][g][rr] + bias[u0 + rr];
                        float sg = 1.f / (1.f + __expf(-vv));
                        o[rr] = f2bf(sg * bf2f(hv[rr]));
                    }
                    *(us4*)(x2st + (size_t)n * 2048 + g * 512 + pofs) = o;
                } else {       // u-gate -> ubuf, packed
                    us4 o;
#pragma unroll
                    for (int rr = 0; rr < 4; ++rr) {
                        float vv = acc[ct][g][rr] + bias[64 + u0 + rr];
                        float sg = 1.f / (1.f + __expf(-vv));
                        o[rr] = f2bf(sg);
                    }
                    *(us4*)(ubuf + (size_t)n * 2048 + g * 512 + pofs) = o;
                }
            } else {
                const int b = g * 16 + lr;
                us4 hv = *(const us4*)(hpk + (size_t)n * 4096 + g * 512 + pofs);
                us4 uv = *(const us4*)(ubuf + (size_t)n * 2048 + g * 512 + pofs);
                float4 o;
#pragma unroll
                for (int rr = 0; rr < 4; ++rr) {
                    float vv = acc[ct][g][rr] + bias[u0 + rr];
                    float e2 = __expf(2.f * vv);
                    float cc = 1.f - 2.f / (e2 + 1.f);
                    float uu = bf2f(uv[rr]);
                    ((float*)&o)[rr] = uu * bf2f(hv[rr]) + (1.f - uu) * cc;
                }
                *(float4*)(outp + (size_t)b * (NN * UU) + (size_t)n * UU + u0) = o;
            }
        }
    }
}

// ---------------------------------------------------------------------------
extern "C" void kernel_launch(void* const* d_in, const int* in_sizes, int n_in,
                              void* d_out, int out_size, void* d_ws, size_t ws_size,
                              hipStream_t stream) {
    const float* inputs  = (const float*)d_in[0];
    const float* hx      = (const float*)d_in[1];
    const float* support = (const float*)d_in[2];
    const float* W_ru    = (const float*)d_in[3];
    const float* b_ru    = (const float*)d_in[4];
    const float* W_c     = (const float*)d_in[5];
    const float* b_c     = (const float*)d_in[6];
    float* out = (float*)d_out;

    char* ws = (char*)d_ws;
    size_t off = 0;
    auto alloc = [&](size_t bytes) -> char* {
        char* p = ws + off;
        off = (off + bytes + 255) & ~(size_t)255;
        return p;
    };
    const size_t BIG = (size_t)NN * 4096;   // elems per wide buffer
    const size_t SML = (size_t)NN * 2048;
    int*            colsI = (int*)  alloc((size_t)NN * MAXNNZ * 4);
    float*          valsF = (float*)alloc((size_t)NN * MAXNNZ * 4);
    int*            cntI  = (int*)  alloc((size_t)NN * 4);
    unsigned short* Wp1   = (unsigned short*)alloc(49152 * 2);
    unsigned short* Wp2   = (unsigned short*)alloc(24576 * 2);
    unsigned short* bufA  = (unsigned short*)alloc(3 * BIG * 2);  // Xall,Z1,Z2
    unsigned short* bufB  = (unsigned short*)alloc(3 * SML * 2);  // X2st,Z1st,Z2st
    unsigned short* ubuf  = (unsigned short*)alloc(SML * 2);
    if (off > ws_size) return;  // workspace too small -> loud validation failure

    unsigned short* Xall = bufA;
    unsigned short* Z1   = bufA + BIG;
    unsigned short* Z2   = bufA + 2 * BIG;
    unsigned short* X2st = bufB;
    unsigned short* Z1st = bufB + SML;
    unsigned short* Z2st = bufB + 2 * SML;
    unsigned short* Hpk  = Xall + 2048;     // packed bf16 h (state half), stride 4096

    // fused builders: ELL (block-per-row) + packed X + packed W in one dispatch
    prep_all<<<20768, 256, 0, stream>>>(support, inputs, hx, W_ru, W_c,
                                        colsI, valsF, cntI, Xall, Wp1, Wp2);

    // gconv1 diffusion over all 4096 columns (8 chunks of 512)
    spmm_kernel<false, 4096><<<8192, 256, 0, stream>>>(colsI, valsF, cntI, Xall, Xall, Z1);
    spmm_kernel<true, 4096><<<8192, 256, 0, stream>>>(colsI, valsF, cntI, Z1, Xall, Z2);
    // gate GEMM -> r*h (X2st, packed) and u (ubuf, packed)
    gemm_kernel<0><<<1024, 512, 0, stream>>>(Xall, BIG, 4096, Xall + 2048, BIG, 4096,
                                             Wp1, b_ru, Hpk, ubuf, X2st, nullptr);
    // gconv2 diffusion: only the 2048 state columns (4 chunks of 512)
    spmm_kernel<false, 2048><<<4096, 256, 0, stream>>>(colsI, valsF, cntI, X2st, X2st, Z1st);
    spmm_kernel<true, 2048><<<4096, 256, 0, stream>>>(colsI, valsF, cntI, Z1st, X2st, Z2st);
    // candidate GEMM + GRU combine -> out
    gemm_kernel<1><<<512, 512, 0, stream>>>(Xall, BIG, 4096, X2st, SML, 2048,
                                            Wp2, b_c, Hpk, ubuf, nullptr, out);
}